// Round 4
// baseline (202.089 us; speedup 1.0000x reference)
//
#include <hip/hip_runtime.h>

// BatchDelayProcessor: out[b,t] = x[b,t]*(1-MIX) + delayed[b,t]*MIX
//   delayed[t<D] = 0 ; delayed[t] = x[t-D] + FB*delayed[t-D]
// => per (b, i) column, a 20-step serial scan over blocks of D samples.
//
// R1: 1-deep prefetch -> 20 serial HBM latencies, 2.44 TB/s (31% peak).
// R2: load-all-then-compute in source, but the machine scheduler sank each
//     load to its use (VGPR stayed 20) -> no change. Latency-bound, not BW.
// R3: sched_barrier(0) between load phase and compute phase pins all 20
//     global_load_dwordx2 before any use -> 20-deep MLP per wave.
//     ~60 VGPR (<=64 keeps 8 waves/SIMD).
// (R3 bench attempt failed on GPU acquisition; resubmitting unchanged.)

constexpr int   kB    = 64;
constexpr int   kT    = 441000;
constexpr int   kD    = 22050;          // delay in samples
constexpr int   kNBLK = kT / kD;        // 20 blocks
constexpr float kFB   = 0.3f;
constexpr float kMIX  = 0.5f;

// float2 granularity: D = 22050 is even and every block offset k*D is even
// -> 8B-aligned float2 everywhere. (float4 impossible: D % 4 == 2.)
constexpr int kHALF  = kD / 2;          // 11025 float2 columns per block
constexpr int kTOTAL = kB * kHALF;      // 705600 threads

__global__ __launch_bounds__(256)
void delay_scan_kernel(const float* __restrict__ x, float* __restrict__ out) {
    int tid = blockIdx.x * blockDim.x + threadIdx.x;
    if (tid >= kTOTAL) return;
    int b = tid / kHALF;                // magic-mul div, once per thread
    int i = tid - b * kHALF;

    const float2* __restrict__ xp =
        reinterpret_cast<const float2*>(x + (size_t)b * kT) + i;
    float2* __restrict__ op =
        reinterpret_cast<float2*>(out + (size_t)b * kT) + i;

    constexpr int kSTRIDE2 = kD / 2;    // float2 stride between blocks

    // Phase 1: issue all 20 independent loads back-to-back (20-deep MLP).
    float2 xv[kNBLK];
    #pragma unroll
    for (int k = 0; k < kNBLK; ++k)
        xv[k] = xp[(size_t)k * kSTRIDE2];

    // Fence: nothing (including these loads) may be rescheduled across this
    // point -> all 20 global_load_dwordx2 are issued before the first use.
    __builtin_amdgcn_sched_barrier(0);

    // Phase 2: serial lag-D recurrence entirely in registers + stores.
    float2 carry; carry.x = 0.0f; carry.y = 0.0f;
    #pragma unroll
    for (int k = 0; k < kNBLK; ++k) {
        float2 o;
        o.x = xv[k].x * (1.0f - kMIX) + carry.x * kMIX;
        o.y = xv[k].y * (1.0f - kMIX) + carry.y * kMIX;
        op[(size_t)k * kSTRIDE2] = o;

        carry.x = xv[k].x + kFB * carry.x;
        carry.y = xv[k].y + kFB * carry.y;
    }
}

extern "C" void kernel_launch(void* const* d_in, const int* in_sizes, int n_in,
                              void* d_out, int out_size, void* d_ws, size_t ws_size,
                              hipStream_t stream) {
    const float* x = (const float*)d_in[0];
    float* out = (float*)d_out;

    constexpr int kBlock = 256;
    constexpr int kGrid  = (kTOTAL + kBlock - 1) / kBlock;  // 2757 blocks
    delay_scan_kernel<<<kGrid, kBlock, 0, stream>>>(x, out);
}